// Round 5
// baseline (1206.500 us; speedup 1.0000x reference)
//
#include <hip/hip_runtime.h>
#include <hip/hip_bf16.h>
#include <cstdint>

#define B_ 8
#define C_ 192
#define N_ 3136
#define K_ 9
#define OC_ 384
#define QT_ 49            // q-tiles per batch (64 q each)
#define MS_ 4             // m-split: quarters of the 13 m-tiles

typedef unsigned int u32;

// ---------------- Kernel A: normalize + transpose + sq ----------------
__global__ __launch_bounds__(256) void prep_k(const float* __restrict__ x,
                                              float* __restrict__ ptsT,
                                              float* __restrict__ xT,
                                              float* __restrict__ sq) {
    int g = blockIdx.x * 256 + threadIdx.x;
    int b = g / N_, n = g % N_;
    const float* xb = x + (size_t)b * C_ * N_ + n;
    float ss = 0.f;
    for (int c = 0; c < C_; ++c) { float v = xb[(size_t)c * N_]; ss = fmaf(v, v, ss); }
    float den = fmaxf(sqrtf(ss), 1e-12f);
    float* pb = ptsT + (size_t)b * C_ * N_ + n;
    float* xrow = xT + (size_t)g * C_;
    float s2 = 0.f;
    for (int c4 = 0; c4 < 48; ++c4) {
        float4 vv;
        float* pv = &vv.x;
        #pragma unroll
        for (int j = 0; j < 4; ++j) {
            int c = 4 * c4 + j;
            float v = xb[(size_t)c * N_];
            float p = v / den;
            pb[(size_t)c * N_] = p;
            pv[j] = v;
            s2 = fmaf(p, p, s2);
        }
        *(float4*)&xrow[4 * c4] = vv;
    }
    sq[g] = s2;
}

// ---------------- Kernel B: fused distance GEMM + partial top-9 ----------------
// Block 64q x 256m-tile, thread tile 8q x 8m, K-chunk 32 -> 40KB LDS ->
// 4 blocks/CU (16 waves). Each block owns m-tiles {s4, s4+4, s4+8, s4+12}
// and emits its partial top-9 per query to global (pkv/pki).
__global__ __launch_bounds__(256) void knn_k(const float* __restrict__ ptsT,
                                             const float* __restrict__ sq,
                                             float* __restrict__ pkv,
                                             int* __restrict__ pki) {
    __shared__ float smem[10240];                 // 40KB: Qc[32][64] | Mc[32][256]; alias dist[64][132]
    float* Qc = smem;                             // 2048 f32
    float* Mc = smem + 2048;                      // 8192 f32
    const int tid = threadIdx.x;
    const int tx = tid & 31;                      // m groups: 4tx and 128+4tx
    const int ty = tid >> 5;                      // q group: 8ty..8ty+7
    const int qs = tid & 63, seg = tid >> 6;      // scan assignment
    const int bid = blockIdx.x;
    const int b = bid / (QT_ * MS_);
    const int rem = bid % (QT_ * MS_);
    const int qt = rem >> 2, s4 = rem & 3;
    const int q0 = qt * 64;
    const float* pb = ptsT + (size_t)b * C_ * N_;
    const float* sqb = sq + b * N_;

    float sqq[8];
    #pragma unroll
    for (int qi = 0; qi < 8; ++qi) sqq[qi] = sqb[q0 + 8 * ty + qi];

    float lv[9]; int li[9];
    #pragma unroll
    for (int r = 0; r < 9; ++r) { lv[r] = INFINITY; li[r] = 0x7fffffff; }
    float worst = INFINITY;

    for (int mt = s4; mt < 13; mt += MS_) {
        const int m0 = mt * 256;
        float acc[8][8];
        #pragma unroll
        for (int qi = 0; qi < 8; ++qi)
            #pragma unroll
            for (int j = 0; j < 8; ++j) acc[qi][j] = 0.f;

        for (int kc = 0; kc < 6; ++kc) {
            __syncthreads();                      // WAR: prior readers of smem done
            // ---- stage Qc: [32 k][64 q], 2 f4/thread ----
            #pragma unroll
            for (int i = 0; i < 2; ++i) {
                int e = tid + i * 256;            // 512 granules
                int row = e >> 4, g4 = e & 15;
                *(float4*)&Qc[row * 64 + 4 * g4] =
                    *(const float4*)&pb[(size_t)(32 * kc + row) * N_ + q0 + 4 * g4];
            }
            // ---- stage Mc: [32 k][256 m], 8 f4/thread ----
            #pragma unroll
            for (int i = 0; i < 8; ++i) {
                int e = tid + i * 256;            // 2048 granules
                int row = e >> 6, g = e & 63;
                int m = m0 + 4 * g;
                float4 v = make_float4(0.f, 0.f, 0.f, 0.f);
                if (m + 4 <= N_)
                    v = *(const float4*)&pb[(size_t)(32 * kc + row) * N_ + m];
                *(float4*)&Mc[row * 256 + 4 * g] = v;
            }
            __syncthreads();
            // ---- GEMM: k strictly ascending 0..191 (acc carried across kc) ----
            #pragma unroll 2
            for (int kk = 0; kk < 32; ++kk) {
                float4 qa  = *(const float4*)&Qc[kk * 64 + 8 * ty];
                float4 qb2 = *(const float4*)&Qc[kk * 64 + 8 * ty + 4];
                float4 mf0 = *(const float4*)&Mc[kk * 256 + 4 * tx];
                float4 mf1 = *(const float4*)&Mc[kk * 256 + 128 + 4 * tx];
                float qv[8] = {qa.x, qa.y, qa.z, qa.w, qb2.x, qb2.y, qb2.z, qb2.w};
                float mv[8] = {mf0.x, mf0.y, mf0.z, mf0.w, mf1.x, mf1.y, mf1.z, mf1.w};
                #pragma unroll
                for (int qi = 0; qi < 8; ++qi)
                    #pragma unroll
                    for (int j = 0; j < 8; ++j)
                        acc[qi][j] = fmaf(qv[qi], mv[j], acc[qi][j]);
            }
        }
        // ---- epilogue + scan in two 128-m phases, dist[64][132] aliases smem ----
        float4 sm0 = *(const float4*)&sqb[m0 + 4 * tx];        // tail over-reads stay in ws
        float4 sm1 = *(const float4*)&sqb[m0 + 128 + 4 * tx];
        float sm[8] = {sm0.x, sm0.y, sm0.z, sm0.w, sm1.x, sm1.y, sm1.z, sm1.w};
        #pragma unroll
        for (int p = 0; p < 2; ++p) {
            __syncthreads();                      // GEMM reads / prev phase scan done
            #pragma unroll
            for (int qi = 0; qi < 8; ++qi) {
                int rr = 8 * ty + qi;
                float d[4];
                #pragma unroll
                for (int c = 0; c < 4; ++c)
                    d[c] = (sqq[qi] - 2.0f * acc[qi][4 * p + c]) + sm[4 * p + c];
                *(float4*)&smem[rr * 132 + 4 * tx] = make_float4(d[0], d[1], d[2], d[3]);
            }
            __syncthreads();
            // scan: thread (qs,seg) scans 32 of this phase's 128 m, rotated start
            for (int j = 0; j < 32; ++j) {
                int ml = seg * 32 + ((j + qs) & 31);
                float d = smem[qs * 132 + ml];
                int m = m0 + 128 * p + ml;
                if (m < N_ && d < worst) {
                    int sm2 = 0; float mx = lv[0];
                    #pragma unroll
                    for (int r = 1; r < 9; ++r) { if (lv[r] > mx) { mx = lv[r]; sm2 = r; } }
                    #pragma unroll
                    for (int r = 0; r < 9; ++r) if (r == sm2) { lv[r] = d; li[r] = m; }
                    float w2 = lv[0];
                    #pragma unroll
                    for (int r = 1; r < 9; ++r) w2 = fmaxf(w2, lv[r]);
                    worst = w2;
                }
            }
        }
    }
    __syncthreads();
    // ---- merge the 4 segment lists per query (stable: val asc, idx asc) ----
    float* Lv = smem;
    int*   Li = (int*)(smem + 2304);
    #pragma unroll
    for (int r = 0; r < 9; ++r) { Lv[tid * 9 + r] = lv[r]; Li[tid * 9 + r] = li[r]; }
    __syncthreads();
    if (tid < 64) {
        size_t base = ((size_t)((b * QT_ + qt) * MS_ + s4) * 64 + tid) * 9;
        for (int r = 0; r < K_; ++r) {
            float best = INFINITY; int bidx = 0x7fffffff; int bp = 0;
            for (int s = 0; s < 4; ++s) {
                int lb = (s * 64 + tid) * 9;
                for (int e = 0; e < 9; ++e) {
                    float v = Lv[lb + e]; int id = Li[lb + e];
                    if (v < best || (v == best && id < bidx)) { best = v; bidx = id; bp = lb + e; }
                }
            }
            pkv[base + r] = best;
            pki[base + r] = bidx;
            Lv[bp] = INFINITY;
        }
    }
}

// ---------------- Kernel B2: merge the 4 quarter lists per query ----------------
__global__ __launch_bounds__(256) void merge_k(const float* __restrict__ pkv,
                                               const int* __restrict__ pki,
                                               int* __restrict__ nn) {
    int g = blockIdx.x * 256 + threadIdx.x;       // 98 blocks * 256 = 25088 exact
    int b = g / N_, n = g % N_;
    int qt = n >> 6, q = n & 63;
    float v[MS_ * 9]; int id[MS_ * 9];
    #pragma unroll
    for (int s = 0; s < MS_; ++s) {
        size_t base = ((size_t)((b * QT_ + qt) * MS_ + s) * 64 + q) * 9;
        #pragma unroll
        for (int e = 0; e < 9; ++e) { v[s * 9 + e] = pkv[base + e]; id[s * 9 + e] = pki[base + e]; }
    }
    int* onn = nn + (size_t)g * K_;
    for (int r = 0; r < K_; ++r) {
        float best = INFINITY; int bidx = 0x7fffffff; int bp = 0;
        #pragma unroll
        for (int e = 0; e < MS_ * 9; ++e) {
            if (v[e] < best || (v[e] == best && id[e] < bidx)) { best = v[e]; bidx = id[e]; bp = e; }
        }
        onn[r] = bidx;
        v[bp] = INFINITY;
    }
}

// ---------------- Kernel C: channels 0..191 (x_i only -> k-independent) ----------------
__global__ __launch_bounds__(256) void convi_k(const float* __restrict__ x,
                                               const float* __restrict__ W,
                                               const float* __restrict__ bias,
                                               float* __restrict__ out) {
    __shared__ float Ws[48 * 96];
    const int orange = blockIdx.x & 3;
    const int nb = blockIdx.x >> 2;
    const int tid = threadIdx.x;
    const int g = nb * 256 + tid;
    const int b = g / N_, n = g % N_;
    const int o0 = orange * 48;
    const int cb = (o0 >= 96) ? 96 : 0;
    for (int i = 0; i < 18; ++i) {
        int e = tid + i * 256;
        Ws[e] = W[o0 * 96 + e];
    }
    __syncthreads();
    const float* xb = x + ((size_t)b * C_ + cb) * N_ + n;
    float xi[96];
    #pragma unroll
    for (int c = 0; c < 96; ++c) xi[c] = xb[(size_t)c * N_];
    float* ob = out + ((size_t)b * OC_ + o0) * N_ + n;
    for (int o = 0; o < 48; ++o) {
        float a = bias[o0 + o];
        #pragma unroll
        for (int c4 = 0; c4 < 24; ++c4) {
            float4 w4 = *(const float4*)&Ws[o * 96 + 4 * c4];
            a = fmaf(w4.x, xi[4*c4+0], a);
            a = fmaf(w4.y, xi[4*c4+1], a);
            a = fmaf(w4.z, xi[4*c4+2], a);
            a = fmaf(w4.w, xi[4*c4+3], a);
        }
        ob[(size_t)o * N_] = fmaxf(a, 0.f);
    }
}

// ---------------- Kernel D: channels 192..383 (x_j - x_i, max over k) ----------------
__device__ __forceinline__ float blo(u32 u) { return __uint_as_float(u << 16); }
__device__ __forceinline__ float bhi(u32 u) { return __uint_as_float(u & 0xffff0000u); }

__device__ __forceinline__ void rd9(float* d, const __hip_bfloat16* base, int c) {
    const u32* p = (const u32*)(base + c * 12);
    u32 u0 = p[0], u1 = p[1], u2 = p[2], u3 = p[3], u4 = p[4];
    d[0] = blo(u0); d[1] = bhi(u0); d[2] = blo(u1); d[3] = bhi(u1);
    d[4] = blo(u2); d[5] = bhi(u2); d[6] = blo(u3); d[7] = bhi(u3); d[8] = blo(u4);
}

__global__ __launch_bounds__(256) void convd_k(const float* __restrict__ xT,
                                               const int* __restrict__ nn,
                                               const float* __restrict__ W,
                                               const float* __restrict__ bias,
                                               float* __restrict__ out) {
    __shared__ __hip_bfloat16 Wb[192 * 104];
    __shared__ __hip_bfloat16 dif[4][192 * 12];
    const int tid = threadIdx.x;
    const int w = tid >> 6, l = tid & 63;
    const int b = blockIdx.x / 196;
    const int n0 = (blockIdx.x % 196) * 16;

    for (int i = 0; i < 72; ++i) {
        int e = tid + i * 256;
        int row = e / 96, j = e % 96;
        Wb[row * 104 + j] = __float2bfloat16(W[(192 + row) * 96 + j]);
    }
    float bo[3];
    #pragma unroll
    for (int oi = 0; oi < 3; ++oi) bo[oi] = bias[192 + l + 64 * oi];
    __syncthreads();

    __hip_bfloat16* df = dif[w];
    const float* xTb = xT + (size_t)b * N_ * C_;
    float mx0[4], mx1[4], mx2[4];

    #pragma unroll
    for (int r = 0; r < 4; ++r) {
        const int n = n0 + 4 * w + r;
        const float* xin = xTb + (size_t)n * C_;
        float xi0 = xin[l], xi1 = xin[l + 64], xi2 = xin[l + 128];
        const int* nb2 = nn + ((size_t)b * N_ + n) * K_;
        __syncthreads();
        #pragma unroll
        for (int k = 0; k < K_; ++k) {
            int idx = nb2[k];
            const float* xj = xTb + (size_t)idx * C_;
            df[(l)      * 12 + k] = __float2bfloat16(xj[l]       - xi0);
            df[(l + 64) * 12 + k] = __float2bfloat16(xj[l + 64]  - xi1);
            df[(l + 128)* 12 + k] = __float2bfloat16(xj[l + 128] - xi2);
        }
        __syncthreads();
        float a0[9], a1[9], a2[9];
        #pragma unroll
        for (int k = 0; k < 9; ++k) { a0[k] = 0.f; a1[k] = 0.f; a2[k] = 0.f; }

        for (int jj = 0; jj < 12; ++jj) {
            float w0[8], w1[8], w2[8];
            {
                uint4 rw = *(const uint4*)(Wb + (size_t)(l)       * 104 + jj * 8);
                w0[0]=blo(rw.x); w0[1]=bhi(rw.x); w0[2]=blo(rw.y); w0[3]=bhi(rw.y);
                w0[4]=blo(rw.z); w0[5]=bhi(rw.z); w0[6]=blo(rw.w); w0[7]=bhi(rw.w);
            }
            {
                uint4 rw = *(const uint4*)(Wb + (size_t)(l + 64)  * 104 + jj * 8);
                w1[0]=blo(rw.x); w1[1]=bhi(rw.x); w1[2]=blo(rw.y); w1[3]=bhi(rw.y);
                w1[4]=blo(rw.z); w1[5]=bhi(rw.z); w1[6]=blo(rw.w); w1[7]=bhi(rw.w);
            }
            {
                uint4 rw = *(const uint4*)(Wb + (size_t)(l + 128) * 104 + jj * 8);
                w2[0]=blo(rw.x); w2[1]=bhi(rw.x); w2[2]=blo(rw.y); w2[3]=bhi(rw.y);
                w2[4]=blo(rw.z); w2[5]=bhi(rw.z); w2[6]=blo(rw.w); w2[7]=bhi(rw.w);
            }
            #pragma unroll
            for (int jr = 0; jr < 8; ++jr) {
                int j = jj * 8 + jr;
                int c0r = j;
                int c2r = 96 + j;
                int c1r = (l >= 32) ? c2r : c0r;
                float d0[9], d1[9], d2[9];
                rd9(d0, df, c0r); rd9(d1, df, c1r); rd9(d2, df, c2r);
                #pragma unroll
                for (int k = 0; k < 9; ++k) {
                    a0[k] = fmaf(w0[jr], d0[k], a0[k]);
                    a1[k] = fmaf(w1[jr], d1[k], a1[k]);
                    a2[k] = fmaf(w2[jr], d2[k], a2[k]);
                }
            }
        }
        float m0 = a0[0] + bo[0], m1 = a1[0] + bo[1], m2 = a2[0] + bo[2];
        #pragma unroll
        for (int k = 1; k < 9; ++k) {
            m0 = fmaxf(m0, a0[k] + bo[0]);
            m1 = fmaxf(m1, a1[k] + bo[1]);
            m2 = fmaxf(m2, a2[k] + bo[2]);
        }
        mx0[r] = fmaxf(m0, 0.f); mx1[r] = fmaxf(m1, 0.f); mx2[r] = fmaxf(m2, 0.f);
    }
    float* ob = out + ((size_t)b * OC_ + 192) * N_ + n0 + 4 * w;
    *(float4*)&ob[(size_t)(l)       * N_] = make_float4(mx0[0], mx0[1], mx0[2], mx0[3]);
    *(float4*)&ob[(size_t)(l + 64)  * N_] = make_float4(mx1[0], mx1[1], mx1[2], mx1[3]);
    *(float4*)&ob[(size_t)(l + 128) * N_] = make_float4(mx2[0], mx2[1], mx2[2], mx2[3]);
}

extern "C" void kernel_launch(void* const* d_in, const int* in_sizes, int n_in,
                              void* d_out, int out_size, void* d_ws, size_t ws_size,
                              hipStream_t stream) {
    (void)in_sizes; (void)n_in; (void)out_size; (void)ws_size;
    const float* x    = (const float*)d_in[0];
    const float* W    = (const float*)d_in[1];
    const float* bias = (const float*)d_in[2];
    float* out = (float*)d_out;

    float* ptsT = (float*)d_ws;                        // 8*192*3136 f32
    float* xT   = ptsT + (size_t)B_ * C_ * N_;         // 8*3136*192 f32
    float* sq   = xT   + (size_t)B_ * N_ * C_;         // 8*3136 f32
    int*   nn   = (int*)(sq + (size_t)B_ * N_);        // 8*3136*9 i32
    float* pkv  = (float*)(nn + (size_t)B_ * N_ * K_); // 392*4*64*9 f32 partial vals
    int*   pki  = (int*)(pkv + (size_t)B_ * QT_ * MS_ * 64 * 9); // partial idx

    hipLaunchKernelGGL(prep_k,  dim3(98),   dim3(256), 0, stream, x, ptsT, xT, sq);
    hipLaunchKernelGGL(knn_k,   dim3(B_ * QT_ * MS_), dim3(256), 0, stream, ptsT, sq, pkv, pki);
    hipLaunchKernelGGL(merge_k, dim3(98),   dim3(256), 0, stream, pkv, pki, nn);
    hipLaunchKernelGGL(convi_k, dim3(392),  dim3(256), 0, stream, x, W, bias, out);
    hipLaunchKernelGGL(convd_k, dim3(1568), dim3(256), 0, stream, xT, nn, W, bias, out);
}